// Round 16
// baseline (84.910 us; speedup 1.0000x reference)
//
#include <hip/hip_runtime.h>
#include <hip/hip_bf16.h>

#define S_LEN 2048
#define E_DIM 512
#define D_DIM 64
#define H_NUM 8
#define B_NUM 2
#define BH_NUM 16
#define NQA 257
#define QAE_W 512                 // clamp-extended QA row width
#define KSPLIT 2
#define NP 8                      // 8 pairs of 128 keys (stride 256, offset ks*128)
#define QTILE 256                 // q-rows per attn block (8 waves x 32)
#define BNDW 176                  // band width (covers 166-wide pair span)

typedef _Float16 half8 __attribute__((ext_vector_type(8)));
typedef float f32x16 __attribute__((ext_vector_type(16)));
typedef unsigned int uint2v __attribute__((ext_vector_type(2)));
typedef unsigned int uint4v __attribute__((ext_vector_type(4)));

static __device__ __forceinline__ f32x16 MFMA(half8 a, half8 b, f32x16 c) {
    return __builtin_amdgcn_mfma_f32_32x32x16_f16(a, b, c, 0, 0, 0);
}
static __device__ __forceinline__ f32x16 ZERO16() {
    f32x16 z;
    #pragma unroll
    for (int i = 0; i < 16; ++i) z[i] = 0.f;
    return z;
}
static __device__ __forceinline__ unsigned int PKRTZ(float a, float b) {
    return __builtin_bit_cast(unsigned int, __builtin_amdgcn_cvt_pkrtz(a, b));
}
static __device__ __forceinline__ half8 CVT8(float4 a, float4 b) {
    uint4v u;
    u[0] = PKRTZ(a.x, a.y); u[1] = PKRTZ(a.z, a.w);
    u[2] = PKRTZ(b.x, b.y); u[3] = PKRTZ(b.z, b.w);
    return __builtin_bit_cast(half8, u);
}

// ---------------------------------------------------------------------------
// cast + transpose weights -> Wht[type][h][n=64][k=512] fp16  (z = 0,1,2)
// type 0 (w_q) scaled by 1/8. z == 3: cast a_k -> fp16.
// ---------------------------------------------------------------------------
__global__ __launch_bounds__(256) void cast_wak_kernel(
    const float* __restrict__ w_q, const float* __restrict__ w_k,
    const float* __restrict__ w_v, const float* __restrict__ w_o,
    const float* __restrict__ a_k,
    _Float16* __restrict__ Wht, _Float16* __restrict__ akh)
{
    __shared__ float T[64][68];
    const int type = blockIdx.z;
    const int t = threadIdx.x;
    if (type == 3) {
        const int bn = blockIdx.y * 8 + blockIdx.x;
        if (bn >= 9) return;
        const int idx = (bn * 256 + t) * 8;
        if (idx < NQA * 64) {
            float4 a = *(const float4*)&a_k[idx];
            float4 b = *(const float4*)&a_k[idx + 4];
            *(half8*)&akh[idx] = CVT8(a, b);
        }
        return;
    }
    const int kt = blockIdx.x, h = blockIdx.y;
    const float* W = (type == 0) ? w_q : (type == 1) ? w_k : w_v;
    const float scale = (type == 0) ? 0.125f : (type == 2 ? w_o[h] : 1.0f);
    const int kr = t >> 2, nseg = (t & 3) * 16;
    #pragma unroll
    for (int i = 0; i < 4; ++i)
        *(float4*)&T[kr][nseg + 4 * i] =
            *(const float4*)&W[((size_t)h * 512 + kt * 64 + kr) * 64 + nseg + 4 * i];
    __syncthreads();
    const int nr = t >> 2, kseg = (t & 3) * 16;
    _Float16* dst = Wht + ((size_t)(type * 8 + h) * 64 + nr) * 512 + kt * 64 + kseg;
    #pragma unroll
    for (int i = 0; i < 2; ++i) {
        half8 o;
        #pragma unroll
        for (int j = 0; j < 8; ++j) o[j] = (_Float16)(T[kseg + 8 * i + j][nr] * scale);
        *(half8*)&dst[8 * i] = o;
    }
}

// ---------------------------------------------------------------------------
// FUSED: cast-X + Q/K/V projections + QA.  grid (16 mt, 16 bh), block 256.
// Stages the fp32 X-chunk ONCE per K-step (in-register fp16 convert) and
// runs all three GEMMs against it (3 accumulator sets). Epilogues write
// Qh/Kh/Vt through a shared ob buffer; QA runs last with Q fragments held
// in registers and a_k staged over the dead W area.
// ---------------------------------------------------------------------------
__global__ __launch_bounds__(256) void proj_qkv_kernel(
    const float* __restrict__ xs, const _Float16* __restrict__ Wht,
    const _Float16* __restrict__ akh,
    _Float16* __restrict__ Qh, _Float16* __restrict__ Kh,
    _Float16* __restrict__ Vt, _Float16* __restrict__ QAe)
{
    __shared__ __align__(16) _Float16 raw[46080];   // 92160 B
    _Float16 (*Xlds)[128][72]    = (_Float16(*)[128][72])raw;            // [2][128][72]
    _Float16 (*Wlds)[3][64][72]  = (_Float16(*)[3][64][72])(raw + 18432);// [2][3][64][72]
    _Float16* ob = raw;                                                  // [128][72] overlay
    _Float16 (*ak)[72] = (_Float16(*)[72])(raw + 18432);                 // [288][72] overlay
    __shared__ _Float16 SLo[128], SHi[128];

    const int mt = blockIdx.x, bh = blockIdx.y;
    const int b = bh >> 3, h = bh & 7;
    const int m0 = mt * 128;
    const int t = threadIdx.x, wid = t >> 6, lane = t & 63;
    const int lq = lane & 31, lh = lane >> 5;

    const float* X = xs + ((size_t)b * S_LEN + m0) * 512;
    const _Float16* W0 = Wht + (size_t)(0 * 8 + h) * 64 * 512;
    const _Float16* W1 = Wht + (size_t)(1 * 8 + h) * 64 * 512;
    const _Float16* W2 = Wht + (size_t)(2 * 8 + h) * 64 * 512;

    const int xrow = t >> 1, xseg = (t & 1) * 32;   // 2 thr/row, 32 cols each
    const int wrow = t >> 2, wseg = (t & 3) * 16;   // 4 thr/row, 16 cols each

    // prologue: chunk 0 -> LDS
    #pragma unroll
    for (int i = 0; i < 4; ++i) {
        float4 a = *(const float4*)&X[(size_t)xrow * 512 + xseg + 8 * i];
        float4 c = *(const float4*)&X[(size_t)xrow * 512 + xseg + 8 * i + 4];
        *(half8*)&Xlds[0][xrow][xseg + 8 * i] = CVT8(a, c);
    }
    #pragma unroll
    for (int i = 0; i < 2; ++i) {
        *(half8*)&Wlds[0][0][wrow][wseg + 8 * i] = *(const half8*)&W0[(size_t)wrow * 512 + wseg + 8 * i];
        *(half8*)&Wlds[0][1][wrow][wseg + 8 * i] = *(const half8*)&W1[(size_t)wrow * 512 + wseg + 8 * i];
        *(half8*)&Wlds[0][2][wrow][wseg + 8 * i] = *(const half8*)&W2[(size_t)wrow * 512 + wseg + 8 * i];
    }
    __syncthreads();

    f32x16 accQ[2], accK[2], accV[2];
    accQ[0] = ZERO16(); accQ[1] = ZERO16();
    accK[0] = ZERO16(); accK[1] = ZERO16();
    accV[0] = ZERO16(); accV[1] = ZERO16();

    int cur = 0;
    for (int c = 0; c < 8; ++c) {
        float4 xa[4], xb[4];
        half8 w0a, w0b, w1a, w1b, w2a, w2b;
        if (c < 7) {
            const int k0 = (c + 1) * 64;
            #pragma unroll
            for (int i = 0; i < 4; ++i) {
                xa[i] = *(const float4*)&X[(size_t)xrow * 512 + k0 + xseg + 8 * i];
                xb[i] = *(const float4*)&X[(size_t)xrow * 512 + k0 + xseg + 8 * i + 4];
            }
            w0a = *(const half8*)&W0[(size_t)wrow * 512 + k0 + wseg];
            w0b = *(const half8*)&W0[(size_t)wrow * 512 + k0 + wseg + 8];
            w1a = *(const half8*)&W1[(size_t)wrow * 512 + k0 + wseg];
            w1b = *(const half8*)&W1[(size_t)wrow * 512 + k0 + wseg + 8];
            w2a = *(const half8*)&W2[(size_t)wrow * 512 + k0 + wseg];
            w2b = *(const half8*)&W2[(size_t)wrow * 512 + k0 + wseg + 8];
        }
        #pragma unroll
        for (int kc = 0; kc < 4; ++kc) {
            half8 a = *(const half8*)&Xlds[cur][wid * 32 + lq][kc * 16 + lh * 8];
            half8 q0 = *(const half8*)&Wlds[cur][0][lq][kc * 16 + lh * 8];
            half8 q1 = *(const half8*)&Wlds[cur][0][32 + lq][kc * 16 + lh * 8];
            accQ[0] = MFMA(a, q0, accQ[0]);
            accQ[1] = MFMA(a, q1, accQ[1]);
            half8 k0f = *(const half8*)&Wlds[cur][1][lq][kc * 16 + lh * 8];
            half8 k1f = *(const half8*)&Wlds[cur][1][32 + lq][kc * 16 + lh * 8];
            accK[0] = MFMA(a, k0f, accK[0]);
            accK[1] = MFMA(a, k1f, accK[1]);
            half8 v0f = *(const half8*)&Wlds[cur][2][lq][kc * 16 + lh * 8];
            half8 v1f = *(const half8*)&Wlds[cur][2][32 + lq][kc * 16 + lh * 8];
            accV[0] = MFMA(a, v0f, accV[0]);
            accV[1] = MFMA(a, v1f, accV[1]);
        }
        if (c < 7) {
            #pragma unroll
            for (int i = 0; i < 4; ++i)
                *(half8*)&Xlds[cur ^ 1][xrow][xseg + 8 * i] = CVT8(xa[i], xb[i]);
            *(half8*)&Wlds[cur ^ 1][0][wrow][wseg]     = w0a;
            *(half8*)&Wlds[cur ^ 1][0][wrow][wseg + 8] = w0b;
            *(half8*)&Wlds[cur ^ 1][1][wrow][wseg]     = w1a;
            *(half8*)&Wlds[cur ^ 1][1][wrow][wseg + 8] = w1b;
            *(half8*)&Wlds[cur ^ 1][2][wrow][wseg]     = w2a;
            *(half8*)&Wlds[cur ^ 1][2][wrow][wseg + 8] = w2b;
        }
        __syncthreads();
        cur ^= 1;
    }

    // stage ak into W overlay (dead after main loop); visible after the
    // barriers inside the epilogue type-loop below.
    for (int r = t; r < 288; r += 256) {
        if (r < NQA) {
            #pragma unroll
            for (int i = 0; i < 8; ++i)
                *(half8*)&ak[r][8 * i] = *(const half8*)&akh[(size_t)r * 64 + 8 * i];
        } else {
            half8 z = {};
            #pragma unroll
            for (int i = 0; i < 8; ++i) *(half8*)&ak[r][8 * i] = z;
        }
    }

    half8 qfr[4];

    // epilogues: Q, K, V through shared ob buffer
    #pragma unroll
    for (int type = 0; type < 3; ++type) {
        const f32x16* acc = (type == 0) ? accQ : (type == 1) ? accK : accV;
        __syncthreads();                      // ob free (Xlds dead / prev type done)
        #pragma unroll
        for (int n = 0; n < 2; ++n)
            #pragma unroll
            for (int r = 0; r < 16; ++r) {
                int row = wid * 32 + (r & 3) + ((r >> 2) << 3) + (lh << 2);
                ob[row * 72 + n * 32 + lq] = (_Float16)acc[n][r];
            }
        __syncthreads();
        if (type == 0) {
            #pragma unroll
            for (int kc = 0; kc < 4; ++kc)
                qfr[kc] = *(const half8*)&ob[(wid * 32 + lq) * 72 + kc * 16 + lh * 8];
        }
        if (type == 2) {
            const int v = t >> 2, sseg = (t & 3) * 32;
            _Float16* dst = Vt + ((size_t)bh * 64 + v) * S_LEN + m0 + sseg;
            #pragma unroll
            for (int i = 0; i < 4; ++i) {
                half8 o;
                #pragma unroll
                for (int j = 0; j < 8; ++j) o[j] = ob[(sseg + 8 * i + j) * 72 + v];
                *(half8*)&dst[8 * i] = o;
            }
        } else {
            _Float16* P = (type == 0) ? Qh : Kh;
            const int row = t >> 1, seg = (t & 1) * 32;
            _Float16* dst = P + ((size_t)bh * S_LEN + m0 + row) * 64 + seg;
            #pragma unroll
            for (int i = 0; i < 4; ++i)
                *(half8*)&dst[8 * i] = *(const half8*)&ob[row * 72 + seg + 8 * i];
        }
    }

    // QA: Q fragments held in qfr; ak already staged
    for (int nsub = 0; nsub < 9; ++nsub) {
        f32x16 qa = ZERO16();
        #pragma unroll
        for (int kc = 0; kc < 4; ++kc) {
            half8 bf = *(const half8*)&ak[nsub * 32 + lq][kc * 16 + lh * 8];
            qa = MFMA(qfr[kc], bf, qa);
        }
        const int col = nsub * 32 + lq;
        if (col < NQA) {
            #pragma unroll
            for (int r = 0; r < 16; ++r) {
                const int row = m0 + wid * 32 + (r & 3) + ((r >> 2) << 3) + (lh << 2);
                const _Float16 v = (_Float16)qa[r];
                QAe[((size_t)bh * S_LEN + row) * QAE_W + col + 128] = v;
                if (col == 0)   SLo[row - m0] = v;
                if (col == 256) SHi[row - m0] = v;
            }
        }
    }
    __syncthreads();

    const int prow = t >> 1, pseg = (t & 1) * 64;
    const _Float16 lo = SLo[prow], hi = SHi[prow];
    half8 vlo, vhi;
    #pragma unroll
    for (int j = 0; j < 8; ++j) { vlo[j] = lo; vhi[j] = hi; }
    _Float16* pb = QAe + ((size_t)bh * S_LEN + m0 + prow) * QAE_W;
    #pragma unroll
    for (int i = 0; i < 8; ++i) {
        *(half8*)&pb[pseg + 8 * i] = vlo;          // cols 0..127
        *(half8*)&pb[384 + pseg + 8 * i] = vhi;    // cols 384..511
    }
}

// ---------------------------------------------------------------------------
// Flash attention (r15, proven): 512-thread blocks, KSPLIT=2, 128-key pairs
// interleaved at stride 256, grid 256 (1/CU, XCD-swizzled).
// ---------------------------------------------------------------------------
__global__ __launch_bounds__(512) void attn_kernel(
    const _Float16* __restrict__ Qh, const _Float16* __restrict__ Kh,
    const _Float16* __restrict__ Vt, const _Float16* __restrict__ QAe,
    _Float16* __restrict__ Po, float2* __restrict__ Ml)
{
    __shared__ __align__(16) char smraw[36864];
    _Float16 (*Klds)[64][72] = (_Float16(*)[64][72])smraw;             // [2][64][72] A/B
    _Float16 (*Vlds)[64][72] = (_Float16(*)[64][72])(smraw + 18432);   // [2][64][72] A/B
    _Float16* Obuf = (_Float16*)smraw;                                 // [256][72]
    __shared__ __align__(16) _Float16 Bnd[8][32][BNDW];                // 90112 B

    const int p0 = blockIdx.x;                 // 0..255
    const int nb = (p0 & 7) * 32 + (p0 >> 3);  // XCD swizzle
    const int bh = nb >> 4;
    const int rem = nb & 15;
    const int qt = rem & 7, ks = rem >> 3;
    const int i0 = qt * QTILE;
    const int kv0 = ks * 128;                  // pair p keys: p*256 + kv0 + [0,128)

    const int t = threadIdx.x, wid = t >> 6, lane = t & 63;
    const int lq = lane & 31, lh = lane >> 5;
    const int i0w = i0 + wid * 32;
    const int qg = i0w + lq;

    half8 qf[4];
    #pragma unroll
    for (int kc = 0; kc < 4; ++kc)
        qf[kc] = *(const half8*)&Qh[((size_t)bh * S_LEN + qg) * 64 + kc * 16 + lh * 8];

    const _Float16* qaeRow = QAe + ((size_t)bh * S_LEN + qg) * QAE_W;
    const float qa_lo = (float)qaeRow[128];   // idx 0
    const float qa_hi = (float)qaeRow[384];   // idx 256
    const _Float16* BndSrc = QAe + ((size_t)bh * S_LEN + i0w) * QAE_W;

    float rm = -1e30f, rl = 0.f;
    f32x16 acco[2];
    acco[0] = ZERO16(); acco[1] = ZERO16();

    // K/V staging: 512 threads, 16B per sub-tile each (K and V)
    const int srow = t >> 3, sseg = (t & 7) * 8;
    const _Float16* Kbase = Kh + (size_t)bh * S_LEN * 64;
    const _Float16* Vbase = Vt + ((size_t)bh * 64 + srow) * S_LEN;

    // band staging: 2 lanes per row, 11 x 16B per lane (176 halves/row)
    const int brow = lane >> 1;
    const int bhalf = (lane & 1) * 88;

    half8 kA, kB, vA, vB, breg[11];
    {
        const int js = kv0;
        *(half8*)&Klds[0][srow][sseg] = *(const half8*)&Kbase[(size_t)(js + srow) * 64 + sseg];
        *(half8*)&Klds[1][srow][sseg] = *(const half8*)&Kbase[(size_t)(js + 64 + srow) * 64 + sseg];
        *(half8*)&Vlds[0][srow][sseg] = *(const half8*)&Vbase[js + sseg];
        *(half8*)&Vlds[1][srow][sseg] = *(const half8*)&Vbase[js + 64 + sseg];
        const int j1 = 256 + kv0;
        kA = *(const half8*)&Kbase[(size_t)(j1 + srow) * 64 + sseg];
        kB = *(const half8*)&Kbase[(size_t)(j1 + 64 + srow) * 64 + sseg];
        vA = *(const half8*)&Vbase[j1 + sseg];
        vB = *(const half8*)&Vbase[j1 + 64 + sseg];
    }
    bool bA_n, bB_n; int cw0_n = 0;
    {
        const int d = kv0 - i0w;
        bA_n = (d > -191) && (d < 159);
        bB_n = (d > -255) && (d < 95);
        if (bA_n || bB_n) {
            const int dFB = bA_n ? d : d + 64;
            cw0_n = (dFB + 225) & ~7;
            cw0_n = cw0_n > 336 ? 336 : cw0_n;
            #pragma unroll
            for (int i = 0; i < 11; ++i)
                breg[i] = *(const half8*)&BndSrc[(size_t)brow * QAE_W + cw0_n + bhalf + i * 8];
        }
    }
    __syncthreads();

    for (int p = 0; p < NP; ++p) {
        const int diff = p * 256 + kv0 - i0w;
        const bool bA = bA_n, bB = bB_n;
        const int cw0 = cw0_n;

        if (bA || bB) {
            #pragma unroll
            for (int i = 0; i < 11; ++i)
                *(half8*)&Bnd[wid][brow][bhalf + i * 8] = breg[i];
        }

        // S^T = K . Q^T  (both sub-tiles, 16 MFMA)
        f32x16 accs[4];
        accs[0] = ZERO16(); accs[1] = ZERO16(); accs[2] = ZERO16(); accs[3] = ZERO16();
        __builtin_amdgcn_s_setprio(1);
        #pragma unroll
        for (int kc = 0; kc < 4; ++kc) {
            half8 a0 = *(const half8*)&Klds[0][lq][kc * 16 + lh * 8];
            half8 a1 = *(const half8*)&Klds[0][32 + lq][kc * 16 + lh * 8];
            half8 b0 = *(const half8*)&Klds[1][lq][kc * 16 + lh * 8];
            half8 b1 = *(const half8*)&Klds[1][32 + lq][kc * 16 + lh * 8];
            accs[0] = MFMA(a0, qf[kc], accs[0]);
            accs[1] = MFMA(a1, qf[kc], accs[1]);
            accs[2] = MFMA(b0, qf[kc], accs[2]);
            accs[3] = MFMA(b1, qf[kc], accs[3]);
        }
        __builtin_amdgcn_s_setprio(0);

        // bias
        float bunif = 0.f;
        if (diff >= 159) {
            bunif = qa_hi;
        } else if (diff <= -255) {
            bunif = qa_lo;
        } else {
            asm volatile("s_waitcnt lgkmcnt(0)" ::: "memory");
            __builtin_amdgcn_sched_barrier(0);
            const int pbA = diff + 256 - cw0 - lq;
            const int pbB = pbA + 64;
            if (bA) {
                #pragma unroll
                for (int m = 0; m < 2; ++m)
                    #pragma unroll
                    for (int r = 0; r < 16; ++r) {
                        const int keyoff = m * 32 + (r & 3) + ((r >> 2) << 3) + (lh << 2);
                        accs[m][r] += (float)Bnd[wid][lq][pbA + keyoff];
                    }
            } else {
                #pragma unroll
                for (int m = 0; m < 2; ++m)
                    #pragma unroll
                    for (int r = 0; r < 16; ++r) accs[m][r] += qa_lo;
            }
            if (bB) {
                #pragma unroll
                for (int m = 0; m < 2; ++m)
                    #pragma unroll
                    for (int r = 0; r < 16; ++r) {
                        const int keyoff = m * 32 + (r & 3) + ((r >> 2) << 3) + (lh << 2);
                        accs[2 + m][r] += (float)Bnd[wid][lq][pbB + keyoff];
                    }
            } else {
                #pragma unroll
                for (int m = 0; m < 2; ++m)
                    #pragma unroll
                    for (int r = 0; r < 16; ++r) accs[2 + m][r] += qa_hi;
            }
        }

        // online softmax over 128 keys
        float t8[8];
        #pragma unroll
        for (int i = 0; i < 8; ++i)
            t8[i] = fmaxf(fmaxf(accs[0][i], accs[0][i + 8]),
                          fmaxf(accs[1][i], accs[1][i + 8]));
        #pragma unroll
        for (int i = 0; i < 8; ++i)
            t8[i] = fmaxf(t8[i], fmaxf(fmaxf(accs[2][i], accs[2][i + 8]),
                                       fmaxf(accs[3][i], accs[3][i + 8])));
        float tmax = fmaxf(fmaxf(fmaxf(t8[0], t8[1]), fmaxf(t8[2], t8[3])),
                           fmaxf(fmaxf(t8[4], t8[5]), fmaxf(t8[6], t8[7])));
        tmax = fmaxf(tmax, __shfl_xor(tmax, 32));
        const float mnew = fmaxf(rm, tmax + bunif);
        const bool resc = __any(mnew > rm);
        const float corr = __expf(rm - mnew);
        const float shift = mnew - bunif;
        rm = mnew;

        #pragma unroll
        for (int s = 0; s < 4; ++s)
            #pragma unroll
            for (int r = 0; r < 16; ++r)
                accs[s][r] = __expf(accs[s][r] - shift);

        float s8[8];
        #pragma unroll
        for (int i = 0; i < 8; ++i)
            s8[i] = ((accs[0][i] + accs[0][i + 8]) + (accs[1][i] + accs[1][i + 8]))
                  + ((accs[2][i] + accs[2][i + 8]) + (accs[3][i] + accs[3][i + 8]));
        float psum = ((s8[0] + s8[1]) + (s8[2] + s8[3])) +
                     ((s8[4] + s8[5]) + (s8[6] + s8[7]));
        psum += __shfl_xor(psum, 32);

        if (resc) {
            rl = rl * corr + psum;
            #pragma unroll
            for (int n = 0; n < 2; ++n)
                #pragma unroll
                for (int r = 0; r < 16; ++r) acco[n][r] *= corr;
        } else {
            rl += psum;
        }

        // pack P -> PV B-fragments (A: accs[0..1], B: accs[2..3])
        half8 pfA[4], pfB[4];
        #pragma unroll
        for (int kc = 0; kc < 4; ++kc) {
            {
                const int m = kc >> 1, rb = (kc & 1) * 8;
                unsigned int a01 = PKRTZ(accs[m][rb + 0], accs[m][rb + 1]);
                unsigned int a45 = PKRTZ(accs[m][rb + 4], accs[m][rb + 5]);
                unsigned int a23 = PKRTZ(accs[m][rb + 2], accs[m][rb + 3]);
                unsigned int a67 = PKRTZ(accs[m][rb + 6], accs[m][rb + 7]);
                uint2v r02 = __builtin_amdgcn_permlane32_swap(a01, a45, false, false);
                uint2v r13 = __builtin_amdgcn_permlane32_swap(a23, a67, false, false);
                uint4v wv;
                wv[0] = r02[0]; wv[1] = r13[0]; wv[2] = r02[1]; wv[3] = r13[1];
                pfA[kc] = __builtin_bit_cast(half8, wv);
            }
            {
                const int m = 2 + (kc >> 1), rb = (kc & 1) * 8;
                unsigned int a01 = PKRTZ(accs[m][rb + 0], accs[m][rb + 1]);
                unsigned int a45 = PKRTZ(accs[m][rb + 4], accs[m][rb + 5]);
                unsigned int a23 = PKRTZ(accs[m][rb + 2], accs[m][rb + 3]);
                unsigned int a67 = PKRTZ(accs[m][rb + 6], accs[m][rb + 7]);
                uint2v r02 = __builtin_amdgcn_permlane32_swap(a01, a45, false, false);
                uint2v r13 = __builtin_amdgcn_permlane32_swap(a23, a67, false, false);
                uint4v wv;
                wv[0] = r02[0]; wv[1] = r13[0]; wv[2] = r02[1]; wv[3] = r13[1];
                pfB[kc] = __builtin_bit_cast(half8, wv);
            }
        }

        // O^T += V_A . P_A^T + V_B . P_B^T  (16 MFMA)
        __builtin_amdgcn_s_setprio(1);
        #pragma unroll
        for (int kc = 0; kc < 4; ++kc) {
            half8 v0 = *(const half8*)&Vlds[0][lq][kc * 16 + lh * 8];
            half8 v1 = *(const half8*)&Vlds[0][32 + lq][kc * 16 + lh * 8];
            acco[0] = MFMA(v0, pfA[kc], acco[0]);
            acco[1] = MFMA(v1, pfA[kc], acco[1]);
        }
        #pragma unroll
        for (int kc = 0; kc < 4; ++kc) {
            half8 v0 = *(const half8*)&Vlds[1][lq][kc * 16 + lh * 8];
            half8 v1 = *(const half8*)&Vlds[1][32 + lq][kc * 16 + lh * 8];
            acco[0] = MFMA(v0, pfB[kc], acco[0]);
            acco[1] = MFMA(v1, pfB[kc], acco[1]);
        }
        __builtin_amdgcn_s_setprio(0);

        // band prefetch for pair p+1
        {
            const int dn = diff + 256;
            bA_n = (p + 1 < NP) && (dn > -191) && (dn < 159);
            bB_n = (p + 1 < NP) && (dn > -255) && (dn < 95);
            if (bA_n || bB_n) {
                const int dFB = bA_n ? dn : dn + 64;
                cw0_n = (dFB + 225) & ~7;
                cw0_n = cw0_n > 336 ? 336 : cw0_n;
                #pragma unroll
                for (int i = 0; i < 11; ++i)
                    breg[i] = *(const half8*)&BndSrc[(size_t)brow * QAE_W + cw0_n + bhalf + i * 8];
            }
        }

        if (p + 1 < NP) {
            __syncthreads();
            *(half8*)&Klds[0][srow][sseg] = kA;
            *(half8*)&Klds[1][srow][sseg] = kB;
            *(half8*)&Vlds[0][srow][sseg] = vA;
            *(half8*)&Vlds[1][srow][sseg] = vB;
            if (p + 2 < NP) {
                const int jn = (p + 2) * 256 + kv0;
                kA = *(const half8*)&Kbase[(size_t)(jn + srow) * 64 + sseg];
                kB = *(const half8*)&Kbase[(size_t)(jn + 64 + srow) * 64 + sseg];
                vA = *(const half8*)&Vbase[jn + sseg];
                vB = *(const half8*)&Vbase[jn + 64 + sseg];
            }
            __syncthreads();
        }
    }

    // epilogue
    __syncthreads();
    const int orow = wid * 32 + lq;
    #pragma unroll
    for (int n = 0; n < 2; ++n)
        #pragma unroll
        for (int rq = 0; rq < 4; ++rq) {
            uint2v hv;
            hv[0] = PKRTZ(acco[n][rq * 4 + 0], acco[n][rq * 4 + 1]);
            hv[1] = PKRTZ(acco[n][rq * 4 + 2], acco[n][rq * 4 + 3]);
            *(uint2v*)&Obuf[(size_t)orow * 72 + n * 32 + rq * 8 + lh * 4] = hv;
        }
    if (lh == 0)
        Ml[((size_t)ks * BH_NUM + bh) * S_LEN + qg] = make_float2(rm, rl);
    asm volatile("s_waitcnt lgkmcnt(0)" ::: "memory");
    __builtin_amdgcn_sched_barrier(0);
    const int rrow = wid * 32 + (lane >> 1);
    const int rseg = (lane & 1) * 32;
    _Float16* dst = Po + (((size_t)ks * BH_NUM + bh) * S_LEN + i0 + rrow) * 64 + rseg;
    #pragma unroll
    for (int i = 0; i < 4; ++i)
        *(half8*)&dst[8 * i] = *(const half8*)&Obuf[(size_t)rrow * 72 + rseg + 8 * i];
}

// ---------------------------------------------------------------------------
// merge partials + combine heads
// ---------------------------------------------------------------------------
__global__ __launch_bounds__(256) void merge_kernel(
    const _Float16* __restrict__ Po, const float2* __restrict__ Ml,
    float* __restrict__ out)
{
    const int b = blockIdx.y;
    const int s = blockIdx.x * 32 + (threadIdx.x >> 3);
    const int v0 = (threadIdx.x & 7) * 8;
    float acc[8] = {0, 0, 0, 0, 0, 0, 0, 0};
    #pragma unroll
    for (int h = 0; h < 8; ++h) {
        const int bh = b * 8 + h;
        float m[KSPLIT], l[KSPLIT];
        #pragma unroll
        for (int p = 0; p < KSPLIT; ++p) {
            const float2 v = Ml[((size_t)p * BH_NUM + bh) * S_LEN + s];
            m[p] = v.x; l[p] = v.y;
        }
        float M = fmaxf(m[0], m[1]);
        float L = 0.f, w[KSPLIT];
        #pragma unroll
        for (int p = 0; p < KSPLIT; ++p) { w[p] = __expf(m[p] - M); L += w[p] * l[p]; }
        const float invL = 1.0f / L;
        #pragma unroll
        for (int p = 0; p < KSPLIT; ++p) {
            half8 o = *(const half8*)&Po[(((size_t)p * BH_NUM + bh) * S_LEN + s) * 64 + v0];
            const float wp = w[p] * invL;
            #pragma unroll
            for (int j = 0; j < 8; ++j) acc[j] += wp * (float)o[j];
        }
    }
    float4 o0 = {acc[0], acc[1], acc[2], acc[3]};
    float4 o1 = {acc[4], acc[5], acc[6], acc[7]};
    *(float4*)&out[((size_t)b * S_LEN + s) * 64 + v0] = o0;
    *(float4*)&out[((size_t)b * S_LEN + s) * 64 + v0 + 4] = o1;
}

// ---------------------------------------------------------------------------
extern "C" void kernel_launch(void* const* d_in, const int* in_sizes, int n_in,
                              void* d_out, int out_size, void* d_ws, size_t ws_size,
                              hipStream_t stream)
{
    const float* xs  = (const float*)d_in[0];
    const float* w_q = (const float*)d_in[1];
    const float* w_k = (const float*)d_in[2];
    const float* w_v = (const float*)d_in[3];
    const float* w_o = (const float*)d_in[4];
    const float* a_k = (const float*)d_in[5];
    float* out = (float*)d_out;

    char* w = (char*)d_ws;
    _Float16* Wht = (_Float16*)w;  w += (size_t)3 * H_NUM * 64 * 512 * 2;         // 1.5 MB
    _Float16* akh = (_Float16*)w;  w += 33024;
    _Float16* Qh  = (_Float16*)w;  w += (size_t)BH_NUM * S_LEN * 64 * 2;
    _Float16* Kh  = (_Float16*)w;  w += (size_t)BH_NUM * S_LEN * 64 * 2;
    _Float16* Vt  = (_Float16*)w;  w += (size_t)BH_NUM * S_LEN * 64 * 2;
    _Float16* QAe = (_Float16*)w;  w += (size_t)BH_NUM * S_LEN * QAE_W * 2 + 1024; // 33.5 MB + slack
    _Float16* Po  = (_Float16*)w;  w += (size_t)KSPLIT * BH_NUM * S_LEN * 64 * 2;  // 8.4 MB
    float2*   Ml  = (float2*)w;                                                    // 0.5 MB

    cast_wak_kernel<<<dim3(8, 8, 4), 256, 0, stream>>>(w_q, w_k, w_v, w_o, a_k, Wht, akh);
    proj_qkv_kernel<<<dim3(16, 16), 256, 0, stream>>>(xs, Wht, akh, Qh, Kh, Vt, QAe);
    attn_kernel<<<256, 512, 0, stream>>>(Qh, Kh, Vt, QAe, Po, Ml);
    merge_kernel<<<dim3(64, 2), 256, 0, stream>>>(Po, Ml, out);
}

// Round 17
// 84.461 us; speedup vs baseline: 1.0053x; 1.0053x over previous
//
#include <hip/hip_runtime.h>
#include <hip/hip_bf16.h>

#define S_LEN 2048
#define E_DIM 512
#define D_DIM 64
#define H_NUM 8
#define B_NUM 2
#define BH_NUM 16
#define NQA 257
#define QAE_W 512                 // clamp-extended QA row width
#define KSPLIT 4
#define NTL 8                     // tiles per block (64 keys, stride 256, offset ks*64)
#define QTILE 256                 // q-rows per attn block (8 waves x 32)
#define BNDW 72                   // per-ROW band width (64 keys + 7 align)

typedef _Float16 half8 __attribute__((ext_vector_type(8)));
typedef float f32x16 __attribute__((ext_vector_type(16)));
typedef unsigned int uint2v __attribute__((ext_vector_type(2)));
typedef unsigned int uint4v __attribute__((ext_vector_type(4)));

static __device__ __forceinline__ f32x16 MFMA(half8 a, half8 b, f32x16 c) {
    return __builtin_amdgcn_mfma_f32_32x32x16_f16(a, b, c, 0, 0, 0);
}
static __device__ __forceinline__ f32x16 ZERO16() {
    f32x16 z;
    #pragma unroll
    for (int i = 0; i < 16; ++i) z[i] = 0.f;
    return z;
}
static __device__ __forceinline__ unsigned int PKRTZ(float a, float b) {
    return __builtin_bit_cast(unsigned int, __builtin_amdgcn_cvt_pkrtz(a, b));
}

// ---------------------------------------------------------------------------
// cast xs (fp32) -> Xh (fp16)
// ---------------------------------------------------------------------------
__global__ __launch_bounds__(256) void cast_x_kernel(
    const float* __restrict__ xs, _Float16* __restrict__ Xh)
{
    const int idx = (blockIdx.x * 256 + threadIdx.x) * 8;
    float4 a = *(const float4*)&xs[idx];
    float4 b = *(const float4*)&xs[idx + 4];
    half8 o;
    o[0] = (_Float16)a.x; o[1] = (_Float16)a.y; o[2] = (_Float16)a.z; o[3] = (_Float16)a.w;
    o[4] = (_Float16)b.x; o[5] = (_Float16)b.y; o[6] = (_Float16)b.z; o[7] = (_Float16)b.w;
    *(half8*)&Xh[idx] = o;
}

// ---------------------------------------------------------------------------
// cast + transpose weights -> Wht[type][h][n=64][k=512] fp16  (z = 0,1,2)
// type 0 (w_q) scaled by 1/8. z == 3: cast a_k -> fp16.
// ---------------------------------------------------------------------------
__global__ __launch_bounds__(256) void cast_wak_kernel(
    const float* __restrict__ w_q, const float* __restrict__ w_k,
    const float* __restrict__ w_v, const float* __restrict__ w_o,
    const float* __restrict__ a_k,
    _Float16* __restrict__ Wht, _Float16* __restrict__ akh)
{
    __shared__ float T[64][68];
    const int type = blockIdx.z;
    const int t = threadIdx.x;
    if (type == 3) {
        const int bn = blockIdx.y * 8 + blockIdx.x;
        if (bn >= 9) return;
        const int idx = (bn * 256 + t) * 8;
        if (idx < NQA * 64) {
            float4 a = *(const float4*)&a_k[idx];
            float4 b = *(const float4*)&a_k[idx + 4];
            half8 o;
            o[0] = (_Float16)a.x; o[1] = (_Float16)a.y; o[2] = (_Float16)a.z; o[3] = (_Float16)a.w;
            o[4] = (_Float16)b.x; o[5] = (_Float16)b.y; o[6] = (_Float16)b.z; o[7] = (_Float16)b.w;
            *(half8*)&akh[idx] = o;
        }
        return;
    }
    const int kt = blockIdx.x, h = blockIdx.y;
    const float* W = (type == 0) ? w_q : (type == 1) ? w_k : w_v;
    const float scale = (type == 0) ? 0.125f : (type == 2 ? w_o[h] : 1.0f);
    const int kr = t >> 2, nseg = (t & 3) * 16;
    #pragma unroll
    for (int i = 0; i < 4; ++i)
        *(float4*)&T[kr][nseg + 4 * i] =
            *(const float4*)&W[((size_t)h * 512 + kt * 64 + kr) * 64 + nseg + 4 * i];
    __syncthreads();
    const int nr = t >> 2, kseg = (t & 3) * 16;
    _Float16* dst = Wht + ((size_t)(type * 8 + h) * 64 + nr) * 512 + kt * 64 + kseg;
    #pragma unroll
    for (int i = 0; i < 2; ++i) {
        half8 o;
        #pragma unroll
        for (int j = 0; j < 8; ++j) o[j] = (_Float16)(T[kseg + 8 * i + j][nr] * scale);
        *(half8*)&dst[8 * i] = o;
    }
}

// ---------------------------------------------------------------------------
// MFMA projections + fused QA (type 0). Same as r15 (proven).
// ---------------------------------------------------------------------------
__global__ __launch_bounds__(256) void proj_mfma_kernel(
    const _Float16* __restrict__ Xh, const _Float16* __restrict__ Wht,
    const _Float16* __restrict__ akh,
    _Float16* __restrict__ Qh, _Float16* __restrict__ Kh,
    _Float16* __restrict__ Vt, _Float16* __restrict__ QAe)
{
    __shared__ __align__(16) _Float16 raw[30208];   // 60416 B
    _Float16 (*Xlds)[128][72] = (_Float16(*)[128][72])raw;          // phase A
    _Float16 (*Wlds)[64][72]  = (_Float16(*)[64][72])(raw + 18432); // phase A
    _Float16* ob  = raw;                                            // [128][72] B
    _Float16 (*ak)[72] = (_Float16(*)[72])(raw + 9216);             // [288][72] B
    _Float16* SLo = raw + 29952;                                    // [128]
    _Float16* SHi = raw + 30080;                                    // [128]

    const int mt = blockIdx.x, bh = blockIdx.y, type = blockIdx.z;
    const int b = bh >> 3, h = bh & 7;
    const int m0 = mt * 128;
    const int t = threadIdx.x, wid = t >> 6, lane = t & 63;
    const int lq = lane & 31, lh = lane >> 5;

    const _Float16* W = Wht + (size_t)(type * 8 + h) * 64 * 512;
    const _Float16* X = Xh + ((size_t)b * S_LEN + m0) * 512;

    const int xrow = t >> 1, xseg = (t & 1) * 32;
    const int wrow = t >> 2, wseg = (t & 3) * 16;

    #pragma unroll
    for (int i = 0; i < 4; ++i)
        *(half8*)&Xlds[0][xrow][xseg + 8 * i] =
            *(const half8*)&X[(size_t)xrow * 512 + xseg + 8 * i];
    #pragma unroll
    for (int i = 0; i < 2; ++i)
        *(half8*)&Wlds[0][wrow][wseg + 8 * i] =
            *(const half8*)&W[(size_t)wrow * 512 + wseg + 8 * i];
    __syncthreads();

    f32x16 acc[2];
    acc[0] = ZERO16(); acc[1] = ZERO16();
    int cur = 0;
    for (int c = 0; c < 8; ++c) {
        half8 xst[4], wst[2];
        if (c < 7) {
            const int k0 = (c + 1) * 64;
            #pragma unroll
            for (int i = 0; i < 4; ++i)
                xst[i] = *(const half8*)&X[(size_t)xrow * 512 + k0 + xseg + 8 * i];
            #pragma unroll
            for (int i = 0; i < 2; ++i)
                wst[i] = *(const half8*)&W[(size_t)wrow * 512 + k0 + wseg + 8 * i];
        }
        #pragma unroll
        for (int kc = 0; kc < 4; ++kc) {
            half8 a  = *(const half8*)&Xlds[cur][wid * 32 + lq][kc * 16 + lh * 8];
            half8 b0 = *(const half8*)&Wlds[cur][lq][kc * 16 + lh * 8];
            half8 b1 = *(const half8*)&Wlds[cur][32 + lq][kc * 16 + lh * 8];
            acc[0] = MFMA(a, b0, acc[0]);
            acc[1] = MFMA(a, b1, acc[1]);
        }
        if (c < 7) {
            #pragma unroll
            for (int i = 0; i < 4; ++i)
                *(half8*)&Xlds[cur ^ 1][xrow][xseg + 8 * i] = xst[i];
            #pragma unroll
            for (int i = 0; i < 2; ++i)
                *(half8*)&Wlds[cur ^ 1][wrow][wseg + 8 * i] = wst[i];
        }
        __syncthreads();
        cur ^= 1;
    }

    // epilogue: acc -> ob
    #pragma unroll
    for (int n = 0; n < 2; ++n)
        #pragma unroll
        for (int r = 0; r < 16; ++r) {
            int row = wid * 32 + (r & 3) + ((r >> 2) << 3) + (lh << 2);
            ob[row * 72 + n * 32 + lq] = (_Float16)acc[n][r];
        }
    __syncthreads();

    if (type == 2) {
        const int v = t >> 2, sseg = (t & 3) * 32;
        _Float16* dst = Vt + ((size_t)bh * 64 + v) * S_LEN + m0 + sseg;
        #pragma unroll
        for (int i = 0; i < 4; ++i) {
            half8 o;
            #pragma unroll
            for (int j = 0; j < 8; ++j) o[j] = ob[(sseg + 8 * i + j) * 72 + v];
            *(half8*)&dst[8 * i] = o;
        }
        return;
    }

    {   // Qh / Kh store
        _Float16* P = (type == 0) ? Qh : Kh;
        const int row = t >> 1, seg = (t & 1) * 32;
        _Float16* dst = P + ((size_t)bh * S_LEN + m0 + row) * 64 + seg;
        #pragma unroll
        for (int i = 0; i < 4; ++i)
            *(half8*)&dst[8 * i] = *(const half8*)&ob[row * 72 + seg + 8 * i];
    }
    if (type != 0) return;

    // -------- phase B: fused QA --------
    for (int r = t; r < 288; r += 256) {
        if (r < NQA) {
            #pragma unroll
            for (int i = 0; i < 8; ++i)
                *(half8*)&ak[r][8 * i] = *(const half8*)&akh[(size_t)r * 64 + 8 * i];
        } else {
            half8 z = {};
            #pragma unroll
            for (int i = 0; i < 8; ++i) *(half8*)&ak[r][8 * i] = z;
        }
    }
    __syncthreads();

    half8 qfr[4];
    #pragma unroll
    for (int kc = 0; kc < 4; ++kc)
        qfr[kc] = *(const half8*)&ob[(wid * 32 + lq) * 72 + kc * 16 + lh * 8];

    for (int nsub = 0; nsub < 9; ++nsub) {
        f32x16 qa = ZERO16();
        #pragma unroll
        for (int kc = 0; kc < 4; ++kc) {
            half8 bf = *(const half8*)&ak[nsub * 32 + lq][kc * 16 + lh * 8];
            qa = MFMA(qfr[kc], bf, qa);
        }
        const int col = nsub * 32 + lq;
        if (col < NQA) {
            #pragma unroll
            for (int r = 0; r < 16; ++r) {
                const int row = m0 + wid * 32 + (r & 3) + ((r >> 2) << 3) + (lh << 2);
                const _Float16 v = (_Float16)qa[r];
                QAe[((size_t)bh * S_LEN + row) * QAE_W + col + 128] = v;
                if (col == 0)   SLo[row - m0] = v;
                if (col == 256) SHi[row - m0] = v;
            }
        }
    }
    __syncthreads();

    const int prow = t >> 1, pseg = (t & 1) * 64;
    const _Float16 lo = SLo[prow], hi = SHi[prow];
    half8 vlo, vhi;
    #pragma unroll
    for (int j = 0; j < 8; ++j) { vlo[j] = lo; vhi[j] = hi; }
    _Float16* pb = QAe + ((size_t)bh * S_LEN + m0 + prow) * QAE_W;
    #pragma unroll
    for (int i = 0; i < 8; ++i) {
        *(half8*)&pb[pseg + 8 * i] = vlo;          // cols 0..127
        *(half8*)&pb[384 + pseg + 8 * i] = vhi;    // cols 384..511
    }
}

// ---------------------------------------------------------------------------
// Flash attention: 512-thread blocks (8 waves x 32 q-rows), KSPLIT=4,
// grid 512 = 2 blocks/CU (XCD-swizzled) -> two INDEPENDENT barrier groups
// per CU hide each other's stalls. LDS = 55.3KB: single-buffered K/V +
// per-ROW bias band Bnd[256][72] (window aligned per q-row, so 72 wide
// suffices; clip handled per-lane via select). 64-key tiles interleaved
// at stride 256 (offset ks*64) for in-band load balance.
// ---------------------------------------------------------------------------
__global__ __launch_bounds__(512, 4) void attn_kernel(
    const _Float16* __restrict__ Qh, const _Float16* __restrict__ Kh,
    const _Float16* __restrict__ Vt, const _Float16* __restrict__ QAe,
    _Float16* __restrict__ Po, float2* __restrict__ Ml)
{
    __shared__ __align__(16) _Float16 Klds[64][72];                    //  9216 B
    __shared__ __align__(16) _Float16 Vlds[64][72];                    //  9216 B
    __shared__ __align__(16) _Float16 Bnd[QTILE][BNDW];                // 36864 B
    _Float16* Obuf = &Bnd[0][0];                                       // [256][72] overlay

    const int p0 = blockIdx.x;                 // 0..511
    const int nb = (p0 & 7) * 64 + (p0 >> 3);  // XCD swizzle
    const int bh = nb >> 5;
    const int rem = nb & 31;
    const int qt = rem & 7, ks = rem >> 3;
    const int i0 = qt * QTILE;
    const int kv0 = ks * 64;                   // tile jt keys: jt*256 + kv0

    const int t = threadIdx.x, wid = t >> 6, lane = t & 63;
    const int lq = lane & 31, lh = lane >> 5;
    const int i0w = i0 + wid * 32;
    const int qg = i0w + lq;

    half8 qf[4];
    #pragma unroll
    for (int kc = 0; kc < 4; ++kc)
        qf[kc] = *(const half8*)&Qh[((size_t)bh * S_LEN + qg) * 64 + kc * 16 + lh * 8];

    const _Float16* qaeRow = QAe + ((size_t)bh * S_LEN + qg) * QAE_W;
    const float qa_lo = (float)qaeRow[128];   // idx 0
    const float qa_hi = (float)qaeRow[384];   // idx 256
    const _Float16* QAeB = QAe + (size_t)bh * S_LEN * QAE_W;

    float rm = -1e30f, rl = 0.f;
    f32x16 acco[2];
    acco[0] = ZERO16(); acco[1] = ZERO16();

    // K/V staging: 512 threads, 16B each
    const int srow = t >> 3, sseg = (t & 7) * 8;
    const _Float16* Kbase = Kh + (size_t)bh * S_LEN * 64;
    const _Float16* Vbase = Vt + ((size_t)bh * 64 + srow) * S_LEN;

    // band staging: 2 threads per row; bsel0 -> halves 0..39, bsel1 -> 40..71
    const int browS = t >> 1, bselS = t & 1;

    half8 kA, vA;
    kA = *(const half8*)&Kbase[(size_t)(kv0 + srow) * 64 + sseg];
    vA = *(const half8*)&Vbase[kv0 + sseg];

    for (int jt = 0; jt < NTL; ++jt) {
        const int J = jt * 256 + kv0;
        const int X0 = J - i0 + 256;

        if (jt) __syncthreads();               // prev tile's K/V/Bnd reads done
        *(half8*)&Klds[srow][sseg] = kA;
        *(half8*)&Vlds[srow][sseg] = vA;

        // stage per-row bias band (only when some row of this block is banded)
        if (X0 >= 66 && X0 <= 638) {
            int a = (X0 - browS) & ~7;
            a = min(max(a, 0), QAE_W - BNDW);
            const _Float16* src = QAeB + (size_t)(i0 + browS) * QAE_W + a;
            if (bselS == 0) {
                half8 b0 = *(const half8*)&src[0];
                half8 b1 = *(const half8*)&src[8];
                half8 b2 = *(const half8*)&src[16];
                half8 b3 = *(const half8*)&src[24];
                half8 b4 = *(const half8*)&src[32];
                *(half8*)&Bnd[browS][0]  = b0;
                *(half8*)&Bnd[browS][8]  = b1;
                *(half8*)&Bnd[browS][16] = b2;
                *(half8*)&Bnd[browS][24] = b3;
                *(half8*)&Bnd[browS][32] = b4;
            } else {
                half8 b0 = *(const half8*)&src[40];
                half8 b1 = *(const half8*)&src[48];
                half8 b2 = *(const half8*)&src[56];
                half8 b3 = *(const half8*)&src[64];
                *(half8*)&Bnd[browS][40] = b0;
                *(half8*)&Bnd[browS][48] = b1;
                *(half8*)&Bnd[browS][56] = b2;
                *(half8*)&Bnd[browS][64] = b3;
            }
        }
        // issue K/V loads for next tile
        if (jt + 1 < NTL) {
            const int Jn = (jt + 1) * 256 + kv0;
            kA = *(const half8*)&Kbase[(size_t)(Jn + srow) * 64 + sseg];
            vA = *(const half8*)&Vbase[Jn + sseg];
        }
        __syncthreads();                       // K/V + band visible

        // S^T = K . Q^T
        f32x16 accs[2];
        accs[0] = ZERO16(); accs[1] = ZERO16();
        __builtin_amdgcn_s_setprio(1);
        #pragma unroll
        for (int kc = 0; kc < 4; ++kc) {
            half8 ka = *(const half8*)&Klds[lq][kc * 16 + lh * 8];
            half8 kb = *(const half8*)&Klds[32 + lq][kc * 16 + lh * 8];
            accs[0] = MFMA(ka, qf[kc], accs[0]);
            accs[1] = MFMA(kb, qf[kc], accs[1]);
        }
        __builtin_amdgcn_s_setprio(0);

        // bias: wave-uniform fast path folds into softmax shift; banded waves
        // do per-lane select (uniform lanes read in-range garbage, selected out)
        const int xw = X0 - wid * 32;          // x_l at lq=0
        float bunif = 0.f;
        if (xw - 31 >= 384) {
            bunif = qa_hi;
        } else if (xw <= 65) {
            bunif = qa_lo;
        } else {
            const int xl = xw - lq;
            const bool lhi = xl >= 384, llo = xl <= 65;
            const float lu = lhi ? qa_hi : qa_lo;
            const bool lband = !(lhi || llo);
            const int rowL = wid * 32 + lq;
            const int base = xl & 7;
            #pragma unroll
            for (int m = 0; m < 2; ++m)
                #pragma unroll
                for (int r = 0; r < 16; ++r) {
                    const int keyoff = m * 32 + (r & 3) + ((r >> 2) << 3) + (lh << 2);
                    const float bv = (float)Bnd[rowL][base + keyoff];
                    accs[m][r] += lband ? bv : lu;
                }
        }

        // online softmax: tree max, shift-folded uniform bias
        float t8[8];
        #pragma unroll
        for (int i = 0; i < 8; ++i)
            t8[i] = fmaxf(fmaxf(accs[0][i], accs[0][i + 8]),
                          fmaxf(accs[1][i], accs[1][i + 8]));
        float tmax = fmaxf(fmaxf(fmaxf(t8[0], t8[1]), fmaxf(t8[2], t8[3])),
                           fmaxf(fmaxf(t8[4], t8[5]), fmaxf(t8[6], t8[7])));
        tmax = fmaxf(tmax, __shfl_xor(tmax, 32));
        const float mnew = fmaxf(rm, tmax + bunif);
        const bool resc = __any(mnew > rm);
        const float corr = __expf(rm - mnew);
        const float shift = mnew - bunif;
        rm = mnew;

        #pragma unroll
        for (int m = 0; m < 2; ++m)
            #pragma unroll
            for (int r = 0; r < 16; ++r)
                accs[m][r] = __expf(accs[m][r] - shift);

        float s8[8];
        #pragma unroll
        for (int i = 0; i < 8; ++i)
            s8[i] = (accs[0][i] + accs[0][i + 8]) + (accs[1][i] + accs[1][i + 8]);
        float psum = ((s8[0] + s8[1]) + (s8[2] + s8[3])) +
                     ((s8[4] + s8[5]) + (s8[6] + s8[7]));
        psum += __shfl_xor(psum, 32);

        if (resc) {
            rl = rl * corr + psum;
            #pragma unroll
            for (int n = 0; n < 2; ++n)
                #pragma unroll
                for (int r = 0; r < 16; ++r) acco[n][r] *= corr;
        } else {
            rl += psum;
        }

        // pack P -> PV B-fragments in-register (cvt_pkrtz + permlane32_swap)
        half8 pf[4];
        #pragma unroll
        for (int kc = 0; kc < 4; ++kc) {
            const int m = kc >> 1, rb = (kc & 1) * 8;
            unsigned int a01 = PKRTZ(accs[m][rb + 0], accs[m][rb + 1]);
            unsigned int a45 = PKRTZ(accs[m][rb + 4], accs[m][rb + 5]);
            unsigned int a23 = PKRTZ(accs[m][rb + 2], accs[m][rb + 3]);
            unsigned int a67 = PKRTZ(accs[m][rb + 6], accs[m][rb + 7]);
            uint2v r02 = __builtin_amdgcn_permlane32_swap(a01, a45, false, false);
            uint2v r13 = __builtin_amdgcn_permlane32_swap(a23, a67, false, false);
            uint4v wv;
            wv[0] = r02[0]; wv[1] = r13[0]; wv[2] = r02[1]; wv[3] = r13[1];
            pf[kc] = __builtin_bit_cast(half8, wv);
        }

        // O^T += V^T . P^T
        __builtin_amdgcn_s_setprio(1);
        #pragma unroll
        for (int kc = 0; kc < 4; ++kc) {
            half8 v0 = *(const half8*)&Vlds[lq][kc * 16 + lh * 8];
            half8 v1 = *(const half8*)&Vlds[32 + lq][kc * 16 + lh * 8];
            acco[0] = MFMA(v0, pf[kc], acco[0]);
            acco[1] = MFMA(v1, pf[kc], acco[1]);
        }
        __builtin_amdgcn_s_setprio(0);
    }

    // epilogue: overlay O-buffer on Bnd
    __syncthreads();
    const int orow = wid * 32 + lq;
    #pragma unroll
    for (int n = 0; n < 2; ++n)
        #pragma unroll
        for (int rq = 0; rq < 4; ++rq) {
            uint2v hv;
            hv[0] = PKRTZ(acco[n][rq * 4 + 0], acco[n][rq * 4 + 1]);
            hv[1] = PKRTZ(acco[n][rq * 4 + 2], acco[n][rq * 4 + 3]);
            *(uint2v*)&Obuf[(size_t)orow * 72 + n * 32 + rq * 8 + lh * 4] = hv;
        }
    if (lh == 0)
        Ml[((size_t)ks * BH_NUM + bh) * S_LEN + qg] = make_float2(rm, rl);
    asm volatile("s_waitcnt lgkmcnt(0)" ::: "memory");
    __builtin_amdgcn_sched_barrier(0);
    const int rrow = wid * 32 + (lane >> 1);
    const int rseg = (lane & 1) * 32;
    _Float16* dst = Po + (((size_t)ks * BH_NUM + bh) * S_LEN + i0 + rrow) * 64 + rseg;
    #pragma unroll
    for (int i = 0; i < 4; ++i)
        *(half8*)&dst[8 * i] = *(const half8*)&Obuf[(size_t)rrow * 72 + rseg + 8 * i];
}

// ---------------------------------------------------------------------------
// merge partials + combine heads (4 partials)
// ---------------------------------------------------------------------------
__global__ __launch_bounds__(256) void merge_kernel(
    const _Float16* __restrict__ Po, const float2* __restrict__ Ml,
    float* __restrict__ out)
{
    const int b = blockIdx.y;
    const int s = blockIdx.x * 32 + (threadIdx.x >> 3);
    const int v0 = (threadIdx.x & 7) * 8;
    float acc[8] = {0, 0, 0, 0, 0, 0, 0, 0};
    #pragma unroll
    for (int h = 0; h < 8; ++h) {
        const int bh = b * 8 + h;
        float m[KSPLIT], l[KSPLIT];
        #pragma unroll
        for (int p = 0; p < KSPLIT; ++p) {
            const float2 v = Ml[((size_t)p * BH_NUM + bh) * S_LEN + s];
            m[p] = v.x; l[p] = v.y;
        }
        float M = fmaxf(fmaxf(m[0], m[1]), fmaxf(m[2], m[3]));
        float L = 0.f, w[KSPLIT];
        #pragma unroll
        for (int p = 0; p < KSPLIT; ++p) { w[p] = __expf(m[p] - M); L += w[p] * l[p]; }
        const float invL = 1.0f / L;
        #pragma unroll
        for (int p = 0; p < KSPLIT; ++p) {
            half8 o = *(const half8*)&Po[(((size_t)p * BH_NUM + bh) * S_LEN + s) * 64 + v0];
            const float wp = w[p] * invL;
            #pragma unroll
            for (int j = 0; j < 8; ++j) acc[j] += wp * (float)o[j];
        }
    }
    float4 o0 = {acc[0], acc[1], acc[2], acc[3]};
    float4 o1 = {acc[4], acc[5], acc[6], acc[7]};
    *(float4*)&out[((size_t)b * S_LEN + s) * 64 + v0] = o0;
    *(float4*)&out[((size_t)b * S_LEN + s) * 64 + v0 + 4] = o1;
}

// ---------------------------------------------------------------------------
extern "C" void kernel_launch(void* const* d_in, const int* in_sizes, int n_in,
                              void* d_out, int out_size, void* d_ws, size_t ws_size,
                              hipStream_t stream)
{
    const float* xs  = (const float*)d_in[0];
    const float* w_q = (const float*)d_in[1];
    const float* w_k = (const float*)d_in[2];
    const float* w_v = (const float*)d_in[3];
    const float* w_o = (const float*)d_in[4];
    const float* a_k = (const float*)d_in[5];
    float* out = (float*)d_out;

    char* w = (char*)d_ws;
    _Float16* Xh  = (_Float16*)w;  w += (size_t)B_NUM * S_LEN * E_DIM * 2;        // 4 MB
    _Float16* Wht = (_Float16*)w;  w += (size_t)3 * H_NUM * 64 * 512 * 2;         // 1.5 MB
    _Float16* akh = (_Float16*)w;  w += 33024;
    _Float16* Qh  = (_Float16*)w;  w += (size_t)BH_NUM * S_LEN * 64 * 2;
    _Float16* Kh  = (_Float16*)w;  w += (size_t)BH_NUM * S_LEN * 64 * 2;
    _Float16* Vt  = (_Float16*)w;  w += (size_t)BH_NUM * S_LEN * 64 * 2;
    _Float16* QAe = (_Float16*)w;  w += (size_t)BH_NUM * S_LEN * QAE_W * 2 + 1024; // 33.5 MB + slack
    _Float16* Po  = (_Float16*)w;  w += (size_t)KSPLIT * BH_NUM * S_LEN * 64 * 2;  // 16.8 MB
    float2*   Ml  = (float2*)w;                                                    // 1 MB

    cast_x_kernel<<<1024, 256, 0, stream>>>(xs, Xh);
    cast_wak_kernel<<<dim3(8, 8, 4), 256, 0, stream>>>(w_q, w_k, w_v, w_o, a_k, Wht, akh);
    proj_mfma_kernel<<<dim3(16, 16, 3), 256, 0, stream>>>(Xh, Wht, akh, Qh, Kh, Vt, QAe);
    attn_kernel<<<512, 512, 0, stream>>>(Qh, Kh, Vt, QAe, Po, Ml);
    merge_kernel<<<dim3(64, 2), 256, 0, stream>>>(Po, Ml, out);
}

// Round 18
// 79.615 us; speedup vs baseline: 1.0665x; 1.0609x over previous
//
#include <hip/hip_runtime.h>
#include <hip/hip_bf16.h>

#define S_LEN 2048
#define E_DIM 512
#define D_DIM 64
#define H_NUM 8
#define B_NUM 2
#define BH_NUM 16
#define NQA 257
#define QAE_W 512                 // clamp-extended QA row width
#define KSPLIT 2
#define NP 8                      // 8 pairs of 128 keys (stride 256, offset ks*128)
#define QTILE 256                 // q-rows per attn block (8 waves x 32)
#define BNDW 176                  // band width (covers 166-wide pair span)

typedef _Float16 half8 __attribute__((ext_vector_type(8)));
typedef float f32x16 __attribute__((ext_vector_type(16)));
typedef unsigned int uint2v __attribute__((ext_vector_type(2)));
typedef unsigned int uint4v __attribute__((ext_vector_type(4)));

static __device__ __forceinline__ f32x16 MFMA(half8 a, half8 b, f32x16 c) {
    return __builtin_amdgcn_mfma_f32_32x32x16_f16(a, b, c, 0, 0, 0);
}
static __device__ __forceinline__ f32x16 ZERO16() {
    f32x16 z;
    #pragma unroll
    for (int i = 0; i < 16; ++i) z[i] = 0.f;
    return z;
}
static __device__ __forceinline__ unsigned int PKRTZ(float a, float b) {
    return __builtin_bit_cast(unsigned int, __builtin_amdgcn_cvt_pkrtz(a, b));
}

// ---------------------------------------------------------------------------
// cast xs (fp32) -> Xh (fp16)
// ---------------------------------------------------------------------------
__global__ __launch_bounds__(256) void cast_x_kernel(
    const float* __restrict__ xs, _Float16* __restrict__ Xh)
{
    const int idx = (blockIdx.x * 256 + threadIdx.x) * 8;
    float4 a = *(const float4*)&xs[idx];
    float4 b = *(const float4*)&xs[idx + 4];
    half8 o;
    o[0] = (_Float16)a.x; o[1] = (_Float16)a.y; o[2] = (_Float16)a.z; o[3] = (_Float16)a.w;
    o[4] = (_Float16)b.x; o[5] = (_Float16)b.y; o[6] = (_Float16)b.z; o[7] = (_Float16)b.w;
    *(half8*)&Xh[idx] = o;
}

// ---------------------------------------------------------------------------
// cast + transpose weights -> Wht[type][h][n=64][k=512] fp16  (z = 0,1,2)
// type 0 (w_q) scaled by 1/8. z == 3: cast a_k -> fp16.
// ---------------------------------------------------------------------------
__global__ __launch_bounds__(256) void cast_wak_kernel(
    const float* __restrict__ w_q, const float* __restrict__ w_k,
    const float* __restrict__ w_v, const float* __restrict__ w_o,
    const float* __restrict__ a_k,
    _Float16* __restrict__ Wht, _Float16* __restrict__ akh)
{
    __shared__ float T[64][68];
    const int type = blockIdx.z;
    const int t = threadIdx.x;
    if (type == 3) {
        const int bn = blockIdx.y * 8 + blockIdx.x;
        if (bn >= 9) return;
        const int idx = (bn * 256 + t) * 8;
        if (idx < NQA * 64) {
            float4 a = *(const float4*)&a_k[idx];
            float4 b = *(const float4*)&a_k[idx + 4];
            half8 o;
            o[0] = (_Float16)a.x; o[1] = (_Float16)a.y; o[2] = (_Float16)a.z; o[3] = (_Float16)a.w;
            o[4] = (_Float16)b.x; o[5] = (_Float16)b.y; o[6] = (_Float16)b.z; o[7] = (_Float16)b.w;
            *(half8*)&akh[idx] = o;
        }
        return;
    }
    const int kt = blockIdx.x, h = blockIdx.y;
    const float* W = (type == 0) ? w_q : (type == 1) ? w_k : w_v;
    const float scale = (type == 0) ? 0.125f : (type == 2 ? w_o[h] : 1.0f);
    const int kr = t >> 2, nseg = (t & 3) * 16;
    #pragma unroll
    for (int i = 0; i < 4; ++i)
        *(float4*)&T[kr][nseg + 4 * i] =
            *(const float4*)&W[((size_t)h * 512 + kt * 64 + kr) * 64 + nseg + 4 * i];
    __syncthreads();
    const int nr = t >> 2, kseg = (t & 3) * 16;
    _Float16* dst = Wht + ((size_t)(type * 8 + h) * 64 + nr) * 512 + kt * 64 + kseg;
    #pragma unroll
    for (int i = 0; i < 2; ++i) {
        half8 o;
        #pragma unroll
        for (int j = 0; j < 8; ++j) o[j] = (_Float16)(T[kseg + 8 * i + j][nr] * scale);
        *(half8*)&dst[8 * i] = o;
    }
}

// ---------------------------------------------------------------------------
// MFMA projections + fused QA (type 0).
// ---------------------------------------------------------------------------
__global__ __launch_bounds__(256) void proj_mfma_kernel(
    const _Float16* __restrict__ Xh, const _Float16* __restrict__ Wht,
    const _Float16* __restrict__ akh,
    _Float16* __restrict__ Qh, _Float16* __restrict__ Kh,
    _Float16* __restrict__ Vt, _Float16* __restrict__ QAe)
{
    __shared__ __align__(16) _Float16 raw[30208];   // 60416 B
    _Float16 (*Xlds)[128][72] = (_Float16(*)[128][72])raw;          // phase A
    _Float16 (*Wlds)[64][72]  = (_Float16(*)[64][72])(raw + 18432); // phase A
    _Float16* ob  = raw;                                            // [128][72] B
    _Float16 (*ak)[72] = (_Float16(*)[72])(raw + 9216);             // [288][72] B
    _Float16* SLo = raw + 29952;                                    // [128]
    _Float16* SHi = raw + 30080;                                    // [128]

    const int mt = blockIdx.x, bh = blockIdx.y, type = blockIdx.z;
    const int b = bh >> 3, h = bh & 7;
    const int m0 = mt * 128;
    const int t = threadIdx.x, wid = t >> 6, lane = t & 63;
    const int lq = lane & 31, lh = lane >> 5;

    const _Float16* W = Wht + (size_t)(type * 8 + h) * 64 * 512;
    const _Float16* X = Xh + ((size_t)b * S_LEN + m0) * 512;

    const int xrow = t >> 1, xseg = (t & 1) * 32;
    const int wrow = t >> 2, wseg = (t & 3) * 16;

    #pragma unroll
    for (int i = 0; i < 4; ++i)
        *(half8*)&Xlds[0][xrow][xseg + 8 * i] =
            *(const half8*)&X[(size_t)xrow * 512 + xseg + 8 * i];
    #pragma unroll
    for (int i = 0; i < 2; ++i)
        *(half8*)&Wlds[0][wrow][wseg + 8 * i] =
            *(const half8*)&W[(size_t)wrow * 512 + wseg + 8 * i];
    __syncthreads();

    f32x16 acc[2];
    acc[0] = ZERO16(); acc[1] = ZERO16();
    int cur = 0;
    for (int c = 0; c < 8; ++c) {
        half8 xst[4], wst[2];
        if (c < 7) {
            const int k0 = (c + 1) * 64;
            #pragma unroll
            for (int i = 0; i < 4; ++i)
                xst[i] = *(const half8*)&X[(size_t)xrow * 512 + k0 + xseg + 8 * i];
            #pragma unroll
            for (int i = 0; i < 2; ++i)
                wst[i] = *(const half8*)&W[(size_t)wrow * 512 + k0 + wseg + 8 * i];
        }
        #pragma unroll
        for (int kc = 0; kc < 4; ++kc) {
            half8 a  = *(const half8*)&Xlds[cur][wid * 32 + lq][kc * 16 + lh * 8];
            half8 b0 = *(const half8*)&Wlds[cur][lq][kc * 16 + lh * 8];
            half8 b1 = *(const half8*)&Wlds[cur][32 + lq][kc * 16 + lh * 8];
            acc[0] = MFMA(a, b0, acc[0]);
            acc[1] = MFMA(a, b1, acc[1]);
        }
        if (c < 7) {
            #pragma unroll
            for (int i = 0; i < 4; ++i)
                *(half8*)&Xlds[cur ^ 1][xrow][xseg + 8 * i] = xst[i];
            #pragma unroll
            for (int i = 0; i < 2; ++i)
                *(half8*)&Wlds[cur ^ 1][wrow][wseg + 8 * i] = wst[i];
        }
        __syncthreads();
        cur ^= 1;
    }

    // epilogue: acc -> ob
    #pragma unroll
    for (int n = 0; n < 2; ++n)
        #pragma unroll
        for (int r = 0; r < 16; ++r) {
            int row = wid * 32 + (r & 3) + ((r >> 2) << 3) + (lh << 2);
            ob[row * 72 + n * 32 + lq] = (_Float16)acc[n][r];
        }
    __syncthreads();

    if (type == 2) {
        const int v = t >> 2, sseg = (t & 3) * 32;
        _Float16* dst = Vt + ((size_t)bh * 64 + v) * S_LEN + m0 + sseg;
        #pragma unroll
        for (int i = 0; i < 4; ++i) {
            half8 o;
            #pragma unroll
            for (int j = 0; j < 8; ++j) o[j] = ob[(sseg + 8 * i + j) * 72 + v];
            *(half8*)&dst[8 * i] = o;
        }
        return;
    }

    {   // Qh / Kh store
        _Float16* P = (type == 0) ? Qh : Kh;
        const int row = t >> 1, seg = (t & 1) * 32;
        _Float16* dst = P + ((size_t)bh * S_LEN + m0 + row) * 64 + seg;
        #pragma unroll
        for (int i = 0; i < 4; ++i)
            *(half8*)&dst[8 * i] = *(const half8*)&ob[row * 72 + seg + 8 * i];
    }
    if (type != 0) return;

    // -------- phase B: fused QA --------
    for (int r = t; r < 288; r += 256) {
        if (r < NQA) {
            #pragma unroll
            for (int i = 0; i < 8; ++i)
                *(half8*)&ak[r][8 * i] = *(const half8*)&akh[(size_t)r * 64 + 8 * i];
        } else {
            half8 z = {};
            #pragma unroll
            for (int i = 0; i < 8; ++i) *(half8*)&ak[r][8 * i] = z;
        }
    }
    __syncthreads();

    half8 qfr[4];
    #pragma unroll
    for (int kc = 0; kc < 4; ++kc)
        qfr[kc] = *(const half8*)&ob[(wid * 32 + lq) * 72 + kc * 16 + lh * 8];

    for (int nsub = 0; nsub < 9; ++nsub) {
        f32x16 qa = ZERO16();
        #pragma unroll
        for (int kc = 0; kc < 4; ++kc) {
            half8 bf = *(const half8*)&ak[nsub * 32 + lq][kc * 16 + lh * 8];
            qa = MFMA(qfr[kc], bf, qa);
        }
        const int col = nsub * 32 + lq;
        if (col < NQA) {
            #pragma unroll
            for (int r = 0; r < 16; ++r) {
                const int row = m0 + wid * 32 + (r & 3) + ((r >> 2) << 3) + (lh << 2);
                const _Float16 v = (_Float16)qa[r];
                QAe[((size_t)bh * S_LEN + row) * QAE_W + col + 128] = v;
                if (col == 0)   SLo[row - m0] = v;
                if (col == 256) SHi[row - m0] = v;
            }
        }
    }
    __syncthreads();

    const int prow = t >> 1, pseg = (t & 1) * 64;
    const _Float16 lo = SLo[prow], hi = SHi[prow];
    half8 vlo, vhi;
    #pragma unroll
    for (int j = 0; j < 8; ++j) { vlo[j] = lo; vhi[j] = hi; }
    _Float16* pb = QAe + ((size_t)bh * S_LEN + m0 + prow) * QAE_W;
    #pragma unroll
    for (int i = 0; i < 8; ++i) {
        *(half8*)&pb[pseg + 8 * i] = vlo;          // cols 0..127
        *(half8*)&pb[384 + pseg + 8 * i] = vhi;    // cols 384..511
    }
}

// ---------------------------------------------------------------------------
// Flash attention: 512-thread blocks (8 waves x 32 q-rows), KSPLIT=2,
// grid 256 (1/CU, XCD-swizzled). 128-key pairs at stride 256 (balanced),
// one softmax per pair; double-buffered K/V; wave-aligned bias band
// prefetched 1 pair ahead; mixed pairs use endpoint constants for the
// uniform half.
// ---------------------------------------------------------------------------
__global__ __launch_bounds__(512) void attn_kernel(
    const _Float16* __restrict__ Qh, const _Float16* __restrict__ Kh,
    const _Float16* __restrict__ Vt, const _Float16* __restrict__ QAe,
    _Float16* __restrict__ Po, float2* __restrict__ Ml)
{
    __shared__ __align__(16) char smraw[36864];
    _Float16 (*Klds)[64][72] = (_Float16(*)[64][72])smraw;             // [2][64][72] A/B
    _Float16 (*Vlds)[64][72] = (_Float16(*)[64][72])(smraw + 18432);   // [2][64][72] A/B
    _Float16* Obuf = (_Float16*)smraw;                                 // [256][72]
    __shared__ __align__(16) _Float16 Bnd[8][32][BNDW];                // 90112 B

    const int p0 = blockIdx.x;                 // 0..255
    const int nb = (p0 & 7) * 32 + (p0 >> 3);  // XCD swizzle
    const int bh = nb >> 4;
    const int rem = nb & 15;
    const int qt = rem & 7, ks = rem >> 3;
    const int i0 = qt * QTILE;
    const int kv0 = ks * 128;                  // pair p keys: p*256 + kv0 + [0,128)

    const int t = threadIdx.x, wid = t >> 6, lane = t & 63;
    const int lq = lane & 31, lh = lane >> 5;
    const int i0w = i0 + wid * 32;
    const int qg = i0w + lq;

    half8 qf[4];
    #pragma unroll
    for (int kc = 0; kc < 4; ++kc)
        qf[kc] = *(const half8*)&Qh[((size_t)bh * S_LEN + qg) * 64 + kc * 16 + lh * 8];

    const _Float16* qaeRow = QAe + ((size_t)bh * S_LEN + qg) * QAE_W;
    const float qa_lo = (float)qaeRow[128];   // idx 0
    const float qa_hi = (float)qaeRow[384];   // idx 256
    const _Float16* BndSrc = QAe + ((size_t)bh * S_LEN + i0w) * QAE_W;

    float rm = -1e30f, rl = 0.f;
    f32x16 acco[2];
    acco[0] = ZERO16(); acco[1] = ZERO16();

    // K/V staging: 512 threads, 16B per sub-tile each (K and V)
    const int srow = t >> 3, sseg = (t & 7) * 8;
    const _Float16* Kbase = Kh + (size_t)bh * S_LEN * 64;
    const _Float16* Vbase = Vt + ((size_t)bh * 64 + srow) * S_LEN;

    // band staging: 2 lanes per row, 11 x 16B per lane (176 halves/row)
    const int brow = lane >> 1;
    const int bhalf = (lane & 1) * 88;

    half8 kA, kB, vA, vB, breg[11];
    {
        const int js = kv0;
        *(half8*)&Klds[0][srow][sseg] = *(const half8*)&Kbase[(size_t)(js + srow) * 64 + sseg];
        *(half8*)&Klds[1][srow][sseg] = *(const half8*)&Kbase[(size_t)(js + 64 + srow) * 64 + sseg];
        *(half8*)&Vlds[0][srow][sseg] = *(const half8*)&Vbase[js + sseg];
        *(half8*)&Vlds[1][srow][sseg] = *(const half8*)&Vbase[js + 64 + sseg];
        const int j1 = 256 + kv0;
        kA = *(const half8*)&Kbase[(size_t)(j1 + srow) * 64 + sseg];
        kB = *(const half8*)&Kbase[(size_t)(j1 + 64 + srow) * 64 + sseg];
        vA = *(const half8*)&Vbase[j1 + sseg];
        vB = *(const half8*)&Vbase[j1 + 64 + sseg];
    }
    bool bA_n, bB_n; int cw0_n = 0;
    {
        const int d = kv0 - i0w;
        bA_n = (d > -191) && (d < 159);
        bB_n = (d > -255) && (d < 95);
        if (bA_n || bB_n) {
            const int dFB = bA_n ? d : d + 64;
            cw0_n = (dFB + 225) & ~7;
            cw0_n = cw0_n > 336 ? 336 : cw0_n;
            #pragma unroll
            for (int i = 0; i < 11; ++i)
                breg[i] = *(const half8*)&BndSrc[(size_t)brow * QAE_W + cw0_n + bhalf + i * 8];
        }
    }
    __syncthreads();

    for (int p = 0; p < NP; ++p) {
        const int diff = p * 256 + kv0 - i0w;
        const bool bA = bA_n, bB = bB_n;
        const int cw0 = cw0_n;

        if (bA || bB) {
            #pragma unroll
            for (int i = 0; i < 11; ++i)
                *(half8*)&Bnd[wid][brow][bhalf + i * 8] = breg[i];
        }

        // S^T = K . Q^T  (both sub-tiles, 16 MFMA)
        f32x16 accs[4];
        accs[0] = ZERO16(); accs[1] = ZERO16(); accs[2] = ZERO16(); accs[3] = ZERO16();
        __builtin_amdgcn_s_setprio(1);
        #pragma unroll
        for (int kc = 0; kc < 4; ++kc) {
            half8 a0 = *(const half8*)&Klds[0][lq][kc * 16 + lh * 8];
            half8 a1 = *(const half8*)&Klds[0][32 + lq][kc * 16 + lh * 8];
            half8 b0 = *(const half8*)&Klds[1][lq][kc * 16 + lh * 8];
            half8 b1 = *(const half8*)&Klds[1][32 + lq][kc * 16 + lh * 8];
            accs[0] = MFMA(a0, qf[kc], accs[0]);
            accs[1] = MFMA(a1, qf[kc], accs[1]);
            accs[2] = MFMA(b0, qf[kc], accs[2]);
            accs[3] = MFMA(b1, qf[kc], accs[3]);
        }
        __builtin_amdgcn_s_setprio(0);

        // bias
        float bunif = 0.f;
        if (diff >= 159) {
            bunif = qa_hi;
        } else if (diff <= -255) {
            bunif = qa_lo;
        } else {
            asm volatile("s_waitcnt lgkmcnt(0)" ::: "memory");
            __builtin_amdgcn_sched_barrier(0);
            const int pbA = diff + 256 - cw0 - lq;
            const int pbB = pbA + 64;
            if (bA) {
                #pragma unroll
                for (int m = 0; m < 2; ++m)
                    #pragma unroll
                    for (int r = 0; r < 16; ++r) {
                        const int keyoff = m * 32 + (r & 3) + ((r >> 2) << 3) + (lh << 2);
                        accs[m][r] += (float)Bnd[wid][lq][pbA + keyoff];
                    }
            } else {
                #pragma unroll
                for (int m = 0; m < 2; ++m)
                    #pragma unroll
                    for (int r = 0; r < 16; ++r) accs[m][r] += qa_lo;
            }
            if (bB) {
                #pragma unroll
                for (int m = 0; m < 2; ++m)
                    #pragma unroll
                    for (int r = 0; r < 16; ++r) {
                        const int keyoff = m * 32 + (r & 3) + ((r >> 2) << 3) + (lh << 2);
                        accs[2 + m][r] += (float)Bnd[wid][lq][pbB + keyoff];
                    }
            } else {
                #pragma unroll
                for (int m = 0; m < 2; ++m)
                    #pragma unroll
                    for (int r = 0; r < 16; ++r) accs[2 + m][r] += qa_hi;
            }
        }

        // online softmax over 128 keys
        float t8[8];
        #pragma unroll
        for (int i = 0; i < 8; ++i)
            t8[i] = fmaxf(fmaxf(accs[0][i], accs[0][i + 8]),
                          fmaxf(accs[1][i], accs[1][i + 8]));
        #pragma unroll
        for (int i = 0; i < 8; ++i)
            t8[i] = fmaxf(t8[i], fmaxf(fmaxf(accs[2][i], accs[2][i + 8]),
                                       fmaxf(accs[3][i], accs[3][i + 8])));
        float tmax = fmaxf(fmaxf(fmaxf(t8[0], t8[1]), fmaxf(t8[2], t8[3])),
                           fmaxf(fmaxf(t8[4], t8[5]), fmaxf(t8[6], t8[7])));
        tmax = fmaxf(tmax, __shfl_xor(tmax, 32));
        const float mnew = fmaxf(rm, tmax + bunif);
        const bool resc = __any(mnew > rm);
        const float corr = __expf(rm - mnew);
        const float shift = mnew - bunif;
        rm = mnew;

        #pragma unroll
        for (int s = 0; s < 4; ++s)
            #pragma unroll
            for (int r = 0; r < 16; ++r)
                accs[s][r] = __expf(accs[s][r] - shift);

        float s8[8];
        #pragma unroll
        for (int i = 0; i < 8; ++i)
            s8[i] = ((accs[0][i] + accs[0][i + 8]) + (accs[1][i] + accs[1][i + 8]))
                  + ((accs[2][i] + accs[2][i + 8]) + (accs[3][i] + accs[3][i + 8]));
        float psum = ((s8[0] + s8[1]) + (s8[2] + s8[3])) +
                     ((s8[4] + s8[5]) + (s8[6] + s8[7]));
        psum += __shfl_xor(psum, 32);

        if (resc) {
            rl = rl * corr + psum;
            #pragma unroll
            for (int n = 0; n < 2; ++n)
                #pragma unroll
                for (int r = 0; r < 16; ++r) acco[n][r] *= corr;
        } else {
            rl += psum;
        }

        // pack P -> PV B-fragments (A: accs[0..1], B: accs[2..3])
        half8 pfA[4], pfB[4];
        #pragma unroll
        for (int kc = 0; kc < 4; ++kc) {
            {
                const int m = kc >> 1, rb = (kc & 1) * 8;
                unsigned int a01 = PKRTZ(accs[m][rb + 0], accs[m][rb + 1]);
                unsigned int a45 = PKRTZ(accs[m][rb + 4], accs[m][rb + 5]);
                unsigned int a23 = PKRTZ(accs[m][rb + 2], accs[m][rb + 3]);
                unsigned int a67 = PKRTZ(accs[m][rb + 6], accs[m][rb + 7]);
                uint2v r02 = __builtin_amdgcn_permlane32_swap(a01, a45, false, false);
                uint2v r13 = __builtin_amdgcn_permlane32_swap(a23, a67, false, false);
                uint4v wv;
                wv[0] = r02[0]; wv[1] = r13[0]; wv[2] = r02[1]; wv[3] = r13[1];
                pfA[kc] = __builtin_bit_cast(half8, wv);
            }
            {
                const int m = 2 + (kc >> 1), rb = (kc & 1) * 8;
                unsigned int a01 = PKRTZ(accs[m][rb + 0], accs[m][rb + 1]);
                unsigned int a45 = PKRTZ(accs[m][rb + 4], accs[m][rb + 5]);
                unsigned int a23 = PKRTZ(accs[m][rb + 2], accs[m][rb + 3]);
                unsigned int a67 = PKRTZ(accs[m][rb + 6], accs[m][rb + 7]);
                uint2v r02 = __builtin_amdgcn_permlane32_swap(a01, a45, false, false);
                uint2v r13 = __builtin_amdgcn_permlane32_swap(a23, a67, false, false);
                uint4v wv;
                wv[0] = r02[0]; wv[1] = r13[0]; wv[2] = r02[1]; wv[3] = r13[1];
                pfB[kc] = __builtin_bit_cast(half8, wv);
            }
        }

        // O^T += V_A . P_A^T + V_B . P_B^T  (16 MFMA)
        __builtin_amdgcn_s_setprio(1);
        #pragma unroll
        for (int kc = 0; kc < 4; ++kc) {
            half8 v0 = *(const half8*)&Vlds[0][lq][kc * 16 + lh * 8];
            half8 v1 = *(const half8*)&Vlds[0][32 + lq][kc * 16 + lh * 8];
            acco[0] = MFMA(v0, pfA[kc], acco[0]);
            acco[1] = MFMA(v1, pfA[kc], acco[1]);
        }
        #pragma unroll
        for (int kc = 0; kc < 4; ++kc) {
            half8 v0 = *(const half8*)&Vlds[1][lq][kc * 16 + lh * 8];
            half8 v1 = *(const half8*)&Vlds[1][32 + lq][kc * 16 + lh * 8];
            acco[0] = MFMA(v0, pfB[kc], acco[0]);
            acco[1] = MFMA(v1, pfB[kc], acco[1]);
        }
        __builtin_amdgcn_s_setprio(0);

        // band prefetch for pair p+1
        {
            const int dn = diff + 256;
            bA_n = (p + 1 < NP) && (dn > -191) && (dn < 159);
            bB_n = (p + 1 < NP) && (dn > -255) && (dn < 95);
            if (bA_n || bB_n) {
                const int dFB = bA_n ? dn : dn + 64;
                cw0_n = (dFB + 225) & ~7;
                cw0_n = cw0_n > 336 ? 336 : cw0_n;
                #pragma unroll
                for (int i = 0; i < 11; ++i)
                    breg[i] = *(const half8*)&BndSrc[(size_t)brow * QAE_W + cw0_n + bhalf + i * 8];
            }
        }

        if (p + 1 < NP) {
            __syncthreads();
            *(half8*)&Klds[0][srow][sseg] = kA;
            *(half8*)&Klds[1][srow][sseg] = kB;
            *(half8*)&Vlds[0][srow][sseg] = vA;
            *(half8*)&Vlds[1][srow][sseg] = vB;
            if (p + 2 < NP) {
                const int jn = (p + 2) * 256 + kv0;
                kA = *(const half8*)&Kbase[(size_t)(jn + srow) * 64 + sseg];
                kB = *(const half8*)&Kbase[(size_t)(jn + 64 + srow) * 64 + sseg];
                vA = *(const half8*)&Vbase[jn + sseg];
                vB = *(const half8*)&Vbase[jn + 64 + sseg];
            }
            __syncthreads();
        }
    }

    // epilogue
    __syncthreads();
    const int orow = wid * 32 + lq;
    #pragma unroll
    for (int n = 0; n < 2; ++n)
        #pragma unroll
        for (int rq = 0; rq < 4; ++rq) {
            uint2v hv;
            hv[0] = PKRTZ(acco[n][rq * 4 + 0], acco[n][rq * 4 + 1]);
            hv[1] = PKRTZ(acco[n][rq * 4 + 2], acco[n][rq * 4 + 3]);
            *(uint2v*)&Obuf[(size_t)orow * 72 + n * 32 + rq * 8 + lh * 4] = hv;
        }
    if (lh == 0)
        Ml[((size_t)ks * BH_NUM + bh) * S_LEN + qg] = make_float2(rm, rl);
    asm volatile("s_waitcnt lgkmcnt(0)" ::: "memory");
    __builtin_amdgcn_sched_barrier(0);
    const int rrow = wid * 32 + (lane >> 1);
    const int rseg = (lane & 1) * 32;
    _Float16* dst = Po + (((size_t)ks * BH_NUM + bh) * S_LEN + i0 + rrow) * 64 + rseg;
    #pragma unroll
    for (int i = 0; i < 4; ++i)
        *(half8*)&dst[8 * i] = *(const half8*)&Obuf[(size_t)rrow * 72 + rseg + 8 * i];
}

// ---------------------------------------------------------------------------
// merge partials + combine heads
// ---------------------------------------------------------------------------
__global__ __launch_bounds__(256) void merge_kernel(
    const _Float16* __restrict__ Po, const float2* __restrict__ Ml,
    float* __restrict__ out)
{
    const int b = blockIdx.y;
    const int s = blockIdx.x * 32 + (threadIdx.x >> 3);
    const int v0 = (threadIdx.x & 7) * 8;
    float acc[8] = {0, 0, 0, 0, 0, 0, 0, 0};
    #pragma unroll
    for (int h = 0; h < 8; ++h) {
        const int bh = b * 8 + h;
        float m[KSPLIT], l[KSPLIT];
        #pragma unroll
        for (int p = 0; p < KSPLIT; ++p) {
            const float2 v = Ml[((size_t)p * BH_NUM + bh) * S_LEN + s];
            m[p] = v.x; l[p] = v.y;
        }
        float M = fmaxf(m[0], m[1]);
        float L = 0.f, w[KSPLIT];
        #pragma unroll
        for (int p = 0; p < KSPLIT; ++p) { w[p] = __expf(m[p] - M); L += w[p] * l[p]; }
        const float invL = 1.0f / L;
        #pragma unroll
        for (int p = 0; p < KSPLIT; ++p) {
            half8 o = *(const half8*)&Po[(((size_t)p * BH_NUM + bh) * S_LEN + s) * 64 + v0];
            const float wp = w[p] * invL;
            #pragma unroll
            for (int j = 0; j < 8; ++j) acc[j] += wp * (float)o[j];
        }
    }
    float4 o0 = {acc[0], acc[1], acc[2], acc[3]};
    float4 o1 = {acc[4], acc[5], acc[6], acc[7]};
    *(float4*)&out[((size_t)b * S_LEN + s) * 64 + v0] = o0;
    *(float4*)&out[((size_t)b * S_LEN + s) * 64 + v0 + 4] = o1;
}

// ---------------------------------------------------------------------------
extern "C" void kernel_launch(void* const* d_in, const int* in_sizes, int n_in,
                              void* d_out, int out_size, void* d_ws, size_t ws_size,
                              hipStream_t stream)
{
    const float* xs  = (const float*)d_in[0];
    const float* w_q = (const float*)d_in[1];
    const float* w_k = (const float*)d_in[2];
    const float* w_v = (const float*)d_in[3];
    const float* w_o = (const float*)d_in[4];
    const float* a_k = (const float*)d_in[5];
    float* out = (float*)d_out;

    char* w = (char*)d_ws;
    _Float16* Xh  = (_Float16*)w;  w += (size_t)B_NUM * S_LEN * E_DIM * 2;        // 4 MB
    _Float16* Wht = (_Float16*)w;  w += (size_t)3 * H_NUM * 64 * 512 * 2;         // 1.5 MB
    _Float16* akh = (_Float16*)w;  w += 33024;
    _Float16* Qh  = (_Float16*)w;  w += (size_t)BH_NUM * S_LEN * 64 * 2;
    _Float16* Kh  = (_Float16*)w;  w += (size_t)BH_NUM * S_LEN * 64 * 2;
    _Float16* Vt  = (_Float16*)w;  w += (size_t)BH_NUM * S_LEN * 64 * 2;
    _Float16* QAe = (_Float16*)w;  w += (size_t)BH_NUM * S_LEN * QAE_W * 2 + 1024; // 33.5 MB + slack
    _Float16* Po  = (_Float16*)w;  w += (size_t)KSPLIT * BH_NUM * S_LEN * 64 * 2;  // 8.4 MB
    float2*   Ml  = (float2*)w;                                                    // 0.5 MB

    cast_x_kernel<<<1024, 256, 0, stream>>>(xs, Xh);
    cast_wak_kernel<<<dim3(8, 8, 4), 256, 0, stream>>>(w_q, w_k, w_v, w_o, a_k, Wht, akh);
    proj_mfma_kernel<<<dim3(16, 16, 3), 256, 0, stream>>>(Xh, Wht, akh, Qh, Kh, Vt, QAe);
    attn_kernel<<<256, 512, 0, stream>>>(Qh, Kh, Vt, QAe, Po, Ml);
    merge_kernel<<<dim3(64, 2), 256, 0, stream>>>(Po, Ml, out);
}